// Round 16
// baseline (91.601 us; speedup 1.0000x reference)
//
#include <hip/hip_runtime.h>
#include <hip/hip_bf16.h>

// GCN layer: out = D^-1/2 A D^-1/2 (X W) + b, per (b,h). B=8,H=8,N=1024,D_IN=D_OUT=64.
//
// Round-14 kernel, third submit (r14/r15 benches were infra failures — the
// broker connection dropped before compile/bench; kernel never ran).
// (1) phase A: double-buffered LDS staging -> ONE barrier per 16-row unit
// (was two); (2) phase C: 1024 blocks, one 16-row group per wave -> 4
// blocks/CU (was 2) for latency hiding. Same arithmetic -> bitwise-same
// output as r13 (84.4 us).
//  k_degsup (1024 blocks, 64 rows): rowsums -> deg -> u4 spill -> X@W*deg tile.
//  k_gcn (1024 blocks): barrier-free u4-dequant MFMA, XCD-pinned per bh.

typedef __attribute__((ext_vector_type(4))) float f32x4;
typedef __attribute__((ext_vector_type(2))) unsigned int u32x2;
typedef __attribute__((ext_vector_type(8))) unsigned short ushort8;
typedef __attribute__((ext_vector_type(4))) unsigned short ushort4v;
typedef __attribute__((ext_vector_type(8))) __bf16 bf16x8;

__device__ __forceinline__ unsigned short f2bf(float f) {
  unsigned int x = __float_as_uint(f);
  unsigned int r = (x + 0x7fffu + ((x >> 16) & 1u)) >> 16;  // RNE, finite inputs
  return (unsigned short)r;
}
__device__ __forceinline__ bf16x8 asbf(ushort8 u) {
  union { ushort8 s; bf16x8 b; } x; x.s = u; return x.b;
}

// ---------------- K1: fused deg + u4 spill + sup tile. Block = (bh, mt): 64 rows.
// adjI chunk layout: [u=bh*64+rg][kt(16)][lane(64)] x 8B, lane=khi*16+rlow holds
// rows rg*16+rlow, cols kt*64+khi*16+0..15 as u4 (q = a*15).
// supF chunk layout: [bh][kt][(s2*4+fj)*64+lane] x 16B, lane=lhi*16+elow holds
// sup[kt*64+s2*32+lhi*8+0..7][fj*16+elow] * deg_row.
template <bool WADJ>
__global__ __launch_bounds__(256) void k_degsup(
    const float* __restrict__ adj, const float* __restrict__ X,
    const float* __restrict__ W, unsigned short* __restrict__ adjI,
    float* __restrict__ deg, unsigned short* __restrict__ supF) {
  const int blk = blockIdx.x;               // bh*16 + mt
  const int bh = blk >> 4, mt = blk & 15, h = bh & 7;
  const int t = threadIdx.x;
  const int r = t >> 4, c = t & 15;         // 16 threads per row
  __shared__ unsigned short sbuf[8192];     // 16 KB: two 8 KB halves (dbuf)
  __shared__ float sdeg[64];

  // ----- 4x 16-row units, dbuf'd: ONE barrier per unit.
  // iter g: W(buf g&1), BAR, R(buf g&1). R(g) vs W(g+2) separated by BAR(g+1).
  for (int g4 = 0; g4 < 4; ++g4) {
    const int u = blk * 4 + g4;             // == bh*64 + mt*4 + g4
    const float* row = adj + ((size_t)u << 14) + ((size_t)r << 10);
    unsigned short* sb = sbuf + ((g4 & 1) << 12);
    f32x4 v[16];
#pragma unroll
    for (int i = 0; i < 16; ++i)            // coalesced, issued back-to-back
      v[i] = *(const f32x4*)(row + (i * 16 + c) * 4);
    float s = 0.f;
#pragma unroll
    for (int i = 0; i < 16; ++i) {
      s += (v[i][0] + v[i][1]) + (v[i][2] + v[i][3]);
      if (WADJ) {
        const unsigned q0 = (unsigned)(v[i][0] * 15.f + 0.5f);
        const unsigned q1 = (unsigned)(v[i][1] * 15.f + 0.5f);
        const unsigned q2 = (unsigned)(v[i][2] * 15.f + 0.5f);
        const unsigned q3 = (unsigned)(v[i][3] * 15.f + 0.5f);
        sb[(r * 256 + i * 16 + c) ^ (((r & 7) << 2) ^ ((r & 3) << 4))] =
            (unsigned short)(q0 | (q1 << 4) | (q2 << 8) | (q3 << 12));
      }
    }
    s += __shfl_xor(s, 1); s += __shfl_xor(s, 2);
    s += __shfl_xor(s, 4); s += __shfl_xor(s, 8);
    if (c == 0) {
      const float d = rsqrtf(s);
      deg[(u << 4) + r] = d;
      sdeg[g4 * 16 + r] = d;
    }
    __syncthreads();                        // quant-writes visible for spill reads
    if (WADJ) {
      ushort4v* base = (ushort4v*)adjI + ((size_t)u << 10);
      const ushort4v* L4 = (const ushort4v*)sb;
#pragma unroll
      for (int j = 0; j < 4; ++j) {
        const int g2 = j * 256 + t;
        const int lane = g2 & 63, kt = g2 >> 6;
        const int rlow = lane & 15, khi = lane >> 4;
        base[g2] = L4[(rlow * 64 + kt * 4 + khi) ^ (rlow & 7) ^ ((rlow & 3) << 2)];
      }
    }
  }
  __syncthreads();                          // last spill reads done before reuse

  // ----- sup tile for (bh, mt): deg_m * (X @ W[h]) -> bf16 B-frag layout
  {
    const int mq = t >> 4, eq = t & 15, m0 = mt * 64;
    const float* Xb = X + ((size_t)bh << 16) + (size_t)(m0 + mq * 4) * 64;
    const float* Wh = W + h * 4096;
    float acc[4][4] = {};
#pragma unroll
    for (int d0 = 0; d0 < 16; ++d0) {
      f32x4 xv[4], wv[4];
#pragma unroll
      for (int i = 0; i < 4; ++i) xv[i] = *(const f32x4*)(Xb + i * 64 + d0 * 4);
#pragma unroll
      for (int dd = 0; dd < 4; ++dd)
        wv[dd] = *(const f32x4*)(Wh + (d0 * 4 + dd) * 64 + eq * 4);
#pragma unroll
      for (int dd = 0; dd < 4; ++dd)
#pragma unroll
        for (int i = 0; i < 4; ++i)
#pragma unroll
          for (int j = 0; j < 4; ++j) acc[i][j] += xv[i][dd] * wv[dd][j];
    }
#pragma unroll
    for (int i = 0; i < 4; ++i) {
      const float dd = sdeg[mq * 4 + i];    // block-local deg (bitwise == global)
      ushort4v u;
      u[0] = f2bf(acc[i][0] * dd); u[1] = f2bf(acc[i][1] * dd);
      u[2] = f2bf(acc[i][2] * dd); u[3] = f2bf(acc[i][3] * dd);
      *(ushort4v*)(&sbuf[(mq * 4 + i) * 64 + eq * 4]) = u;
    }
    __syncthreads();
    ushort8* dst = (ushort8*)supF + ((size_t)blk << 9);
#pragma unroll
    for (int p = 0; p < 2; ++p) {
      const int cid = t + p * 256;
      const int elow = cid & 15, lhi = (cid >> 4) & 3, fj = (cid >> 6) & 3, s2 = cid >> 8;
      ushort8 u;
#pragma unroll
      for (int jj = 0; jj < 8; ++jj)
        u[jj] = sbuf[(s2 * 32 + lhi * 8 + jj) * 64 + fj * 16 + elow];
      dst[(s2 * 4 + fj) * 64 + lhi * 16 + elow] = u;
    }
  }
}

// ---------------- K2: out = deg_n*(1/15) * (dequant4(adjI) @ supF) + bias.
// Barrier-free, 1024 blocks (4/CU): bh=(i&7)+8*((i>>3)&7) (XCD-pinned),
// rt16=i>>6; wave w owns ONE 16-row group rg=rt16*4+w. E/O register dbuf.
template <bool PRE>
__global__ __launch_bounds__(256) void k_gcn(const float* __restrict__ adj,
                                             const unsigned short* __restrict__ adjI,
                                             const unsigned short* __restrict__ supF,
                                             const float* __restrict__ deg,
                                             const float* __restrict__ bias,
                                             float* __restrict__ out) {
  const int i = blockIdx.x;
  const int bh = (i & 7) + 8 * ((i >> 3) & 7), rt16 = i >> 6;
  const int t = threadIdx.x, w = t >> 6, l = t & 63;
  const int rg = rt16 * 4 + w;              // one 16-row group per wave
  const int hh = (l >> 4) & 1;
  const int lane20 = ((l >> 5) << 4) + (l & 15);
  const u32x2* aB = (const u32x2*)adjI + ((size_t)(bh * 64 + rg) << 10);
  const ushort8* bB = (const ushort8*)supF + ((size_t)bh << 13);

  auto loadA = [&](int kt, u32x2* qa) {
    qa[0] = aB[kt * 64 + lane20];
    qa[1] = aB[kt * 64 + lane20 + 32];
  };
  auto loadAf32 = [&](int kt, ushort8* fa) {
#pragma unroll
    for (int s2 = 0; s2 < 2; ++s2) {
      const float* src = adj + ((size_t)bh << 20) +
                         ((size_t)(rg * 16 + (l & 15)) << 10) +
                         kt * 64 + s2 * 32 + ((l >> 4) << 3);
      f32x4 a = *(const f32x4*)(src);
      f32x4 b = *(const f32x4*)(src + 4);
      ushort8 u;
      u[0] = f2bf(a[0]); u[1] = f2bf(a[1]); u[2] = f2bf(a[2]); u[3] = f2bf(a[3]);
      u[4] = f2bf(b[0]); u[5] = f2bf(b[1]); u[6] = f2bf(b[2]); u[7] = f2bf(b[3]);
      fa[s2] = u;
    }
  };
  auto loadB = [&](int kt, ushort8* vb) {
#pragma unroll
    for (int c2 = 0; c2 < 8; ++c2) vb[c2] = bB[(size_t)kt * 512 + c2 * 64 + l];
  };

  f32x4 acc[4] = {};
  auto compute = [&](u32x2* qa, ushort8* fa, ushort8* vb) {
#pragma unroll
    for (int s2 = 0; s2 < 2; ++s2) {
      bf16x8 a;
      if (PRE) {
        const unsigned v = qa[s2][hh];
        ushort8 ua;
#pragma unroll
        for (int e = 0; e < 8; ++e)
          ua[e] = (unsigned short)(__float_as_uint((float)((v >> (4 * e)) & 15u)) >> 16);
        a = asbf(ua);
      } else {
        a = asbf(fa[s2]);
      }
#pragma unroll
      for (int fj = 0; fj < 4; ++fj)
        acc[fj] = __builtin_amdgcn_mfma_f32_16x16x32_bf16(
            a, asbf(vb[s2 * 4 + fj]), acc[fj], 0, 0, 0);
    }
  };

  u32x2 qaE[2], qaO[2];
  ushort8 faE[2], faO[2], vbE[8], vbO[8];
  if (PRE) loadA(0, qaE); else loadAf32(0, faE);
  loadB(0, vbE);
  for (int kt = 0; kt < 16; kt += 2) {       // E/O static reg sets (rule #20)
    if (kt + 1 < 16) { if (PRE) loadA(kt + 1, qaO); else loadAf32(kt + 1, faO); loadB(kt + 1, vbO); }
    compute(qaE, faE, vbE);
    if (kt + 2 < 16) { if (PRE) loadA(kt + 2, qaE); else loadAf32(kt + 2, faE); loadB(kt + 2, vbE); }
    compute(qaO, faO, vbO);
  }

  const int el = l & 15, q4 = (l >> 4) * 4;
  const float qs = PRE ? (1.f / 15.f) : 1.f;
  const int rowb = rg * 16 + q4;
  float dgv[4];
#pragma unroll
  for (int reg = 0; reg < 4; ++reg)
    dgv[reg] = deg[(bh << 10) + rowb + reg] * qs;
#pragma unroll
  for (int fj = 0; fj < 4; ++fj) {
    const float bv = bias[fj * 16 + el];
#pragma unroll
    for (int reg = 0; reg < 4; ++reg) {
      const float val = acc[fj][reg] * dgv[reg] + bv;
      __builtin_nontemporal_store(
          val, out + ((size_t)bh << 16) + (size_t)(rowb + reg) * 64 + fj * 16 + el);
    }
  }
}

extern "C" void kernel_launch(void* const* d_in, const int* in_sizes, int n_in,
                              void* d_out, int out_size, void* d_ws, size_t ws_size,
                              hipStream_t stream) {
  const float* X    = (const float*)d_in[0];  // [8,8,1024,64]
  const float* adj  = (const float*)d_in[1];  // [8,8,1024,1024]
  const float* W    = (const float*)d_in[2];  // [8,64,64]
  const float* bias = (const float*)d_in[3];  // [64]
  float* out = (float*)d_out;

  float* deg = (float*)d_ws;                                         // 256 KB
  unsigned short* supF = (unsigned short*)((char*)d_ws + 262144);    // 8 MB
  unsigned short* adjI = (unsigned short*)((char*)d_ws + 8650752);   // 32 MB (u4)
  const bool pre = ws_size >= 42205184ull;

  if (pre) {
    k_degsup<true><<<dim3(1024), dim3(256), 0, stream>>>(adj, X, W, adjI, deg, supF);
    k_gcn<true><<<dim3(1024), dim3(256), 0, stream>>>(adj, adjI, supF, deg, bias, out);
  } else {
    k_degsup<false><<<dim3(1024), dim3(256), 0, stream>>>(adj, X, W, adjI, deg, supF);
    k_gcn<false><<<dim3(1024), dim3(256), 0, stream>>>(adj, adjI, supF, deg, bias, out);
  }
}

// Round 17
// 84.348 us; speedup vs baseline: 1.0860x; 1.0860x over previous
//
#include <hip/hip_runtime.h>
#include <hip/hip_bf16.h>

// GCN layer: out = D^-1/2 A D^-1/2 (X W) + b, per (b,h). B=8,H=8,N=1024,D_IN=D_OUT=64.
//
// Round-17 isolation: r16 (A-dbuf + C-regrid) regressed 84.4 -> 91.6 vs r13.
// This round keeps ONE change only: phase-A dbuf (k_degsup as r16). Phase C
// reverts verbatim to r13's k_gcn (512 blocks, 2 row-groups/wave, higher
// arithmetic intensity per wave). Readout: ~81-84 -> C-regrid was the
// regressor; >=88 -> A-dbuf was -> full r13 revert next.

typedef __attribute__((ext_vector_type(4))) float f32x4;
typedef __attribute__((ext_vector_type(2))) unsigned int u32x2;
typedef __attribute__((ext_vector_type(8))) unsigned short ushort8;
typedef __attribute__((ext_vector_type(4))) unsigned short ushort4v;
typedef __attribute__((ext_vector_type(8))) __bf16 bf16x8;

__device__ __forceinline__ unsigned short f2bf(float f) {
  unsigned int x = __float_as_uint(f);
  unsigned int r = (x + 0x7fffu + ((x >> 16) & 1u)) >> 16;  // RNE, finite inputs
  return (unsigned short)r;
}
__device__ __forceinline__ bf16x8 asbf(ushort8 u) {
  union { ushort8 s; bf16x8 b; } x; x.s = u; return x.b;
}

// ---------------- K1: fused deg + u4 spill + sup tile (r16's dbuf version).
// Block = (bh, mt): 64 rows. adjI chunk layout: [u=bh*64+rg][kt(16)][lane(64)]
// x 8B, lane=khi*16+rlow holds rows rg*16+rlow, cols kt*64+khi*16+0..15 as u4.
// supF chunk layout: [bh][kt][(s2*4+fj)*64+lane] x 16B, lane=lhi*16+elow holds
// sup[kt*64+s2*32+lhi*8+0..7][fj*16+elow] * deg_row.
template <bool WADJ>
__global__ __launch_bounds__(256) void k_degsup(
    const float* __restrict__ adj, const float* __restrict__ X,
    const float* __restrict__ W, unsigned short* __restrict__ adjI,
    float* __restrict__ deg, unsigned short* __restrict__ supF) {
  const int blk = blockIdx.x;               // bh*16 + mt
  const int bh = blk >> 4, mt = blk & 15, h = bh & 7;
  const int t = threadIdx.x;
  const int r = t >> 4, c = t & 15;         // 16 threads per row
  __shared__ unsigned short sbuf[8192];     // 16 KB: two 8 KB halves (dbuf)
  __shared__ float sdeg[64];

  // ----- 4x 16-row units, dbuf'd: ONE barrier per unit.
  for (int g4 = 0; g4 < 4; ++g4) {
    const int u = blk * 4 + g4;             // == bh*64 + mt*4 + g4
    const float* row = adj + ((size_t)u << 14) + ((size_t)r << 10);
    unsigned short* sb = sbuf + ((g4 & 1) << 12);
    f32x4 v[16];
#pragma unroll
    for (int i = 0; i < 16; ++i)            // coalesced, issued back-to-back
      v[i] = *(const f32x4*)(row + (i * 16 + c) * 4);
    float s = 0.f;
#pragma unroll
    for (int i = 0; i < 16; ++i) {
      s += (v[i][0] + v[i][1]) + (v[i][2] + v[i][3]);
      if (WADJ) {
        const unsigned q0 = (unsigned)(v[i][0] * 15.f + 0.5f);
        const unsigned q1 = (unsigned)(v[i][1] * 15.f + 0.5f);
        const unsigned q2 = (unsigned)(v[i][2] * 15.f + 0.5f);
        const unsigned q3 = (unsigned)(v[i][3] * 15.f + 0.5f);
        sb[(r * 256 + i * 16 + c) ^ (((r & 7) << 2) ^ ((r & 3) << 4))] =
            (unsigned short)(q0 | (q1 << 4) | (q2 << 8) | (q3 << 12));
      }
    }
    s += __shfl_xor(s, 1); s += __shfl_xor(s, 2);
    s += __shfl_xor(s, 4); s += __shfl_xor(s, 8);
    if (c == 0) {
      const float d = rsqrtf(s);
      deg[(u << 4) + r] = d;
      sdeg[g4 * 16 + r] = d;
    }
    __syncthreads();                        // quant-writes visible for spill reads
    if (WADJ) {
      ushort4v* base = (ushort4v*)adjI + ((size_t)u << 10);
      const ushort4v* L4 = (const ushort4v*)sb;
#pragma unroll
      for (int j = 0; j < 4; ++j) {
        const int g2 = j * 256 + t;
        const int lane = g2 & 63, kt = g2 >> 6;
        const int rlow = lane & 15, khi = lane >> 4;
        base[g2] = L4[(rlow * 64 + kt * 4 + khi) ^ (rlow & 7) ^ ((rlow & 3) << 2)];
      }
    }
  }
  __syncthreads();                          // last spill reads done before reuse

  // ----- sup tile for (bh, mt): deg_m * (X @ W[h]) -> bf16 B-frag layout
  {
    const int mq = t >> 4, eq = t & 15, m0 = mt * 64;
    const float* Xb = X + ((size_t)bh << 16) + (size_t)(m0 + mq * 4) * 64;
    const float* Wh = W + h * 4096;
    float acc[4][4] = {};
#pragma unroll
    for (int d0 = 0; d0 < 16; ++d0) {
      f32x4 xv[4], wv[4];
#pragma unroll
      for (int i = 0; i < 4; ++i) xv[i] = *(const f32x4*)(Xb + i * 64 + d0 * 4);
#pragma unroll
      for (int dd = 0; dd < 4; ++dd)
        wv[dd] = *(const f32x4*)(Wh + (d0 * 4 + dd) * 64 + eq * 4);
#pragma unroll
      for (int dd = 0; dd < 4; ++dd)
#pragma unroll
        for (int i = 0; i < 4; ++i)
#pragma unroll
          for (int j = 0; j < 4; ++j) acc[i][j] += xv[i][dd] * wv[dd][j];
    }
#pragma unroll
    for (int i = 0; i < 4; ++i) {
      const float dd = sdeg[mq * 4 + i];    // block-local deg (bitwise == global)
      ushort4v u;
      u[0] = f2bf(acc[i][0] * dd); u[1] = f2bf(acc[i][1] * dd);
      u[2] = f2bf(acc[i][2] * dd); u[3] = f2bf(acc[i][3] * dd);
      *(ushort4v*)(&sbuf[(mq * 4 + i) * 64 + eq * 4]) = u;
    }
    __syncthreads();
    ushort8* dst = (ushort8*)supF + ((size_t)blk << 9);
#pragma unroll
    for (int p = 0; p < 2; ++p) {
      const int cid = t + p * 256;
      const int elow = cid & 15, lhi = (cid >> 4) & 3, fj = (cid >> 6) & 3, s2 = cid >> 8;
      ushort8 u;
#pragma unroll
      for (int jj = 0; jj < 8; ++jj)
        u[jj] = sbuf[(s2 * 32 + lhi * 8 + jj) * 64 + fj * 16 + elow];
      dst[(s2 * 4 + fj) * 64 + lhi * 16 + elow] = u;
    }
  }
}

// ---------------- K2: out = deg_n*(1/15) * (dequant4(adjI) @ supF) + bias.
// r13's version verbatim: barrier-free, 512 blocks, wave owns TWO 16-row
// groups (rg0, rg0+1): 16 MFMAs per kt against 8 B-chunk loads.
template <bool PRE>
__global__ __launch_bounds__(256) void k_gcn(const float* __restrict__ adj,
                                             const unsigned short* __restrict__ adjI,
                                             const unsigned short* __restrict__ supF,
                                             const float* __restrict__ deg,
                                             const float* __restrict__ bias,
                                             float* __restrict__ out) {
  const int i = blockIdx.x;
  const int bh = (i & 7) + 8 * ((i >> 3) & 7), rt8 = i >> 6;
  const int t = threadIdx.x, w = t >> 6, l = t & 63;
  const int rg0 = rt8 * 8 + w * 2;
  const int hh = (l >> 4) & 1;
  const int lane20 = ((l >> 5) << 4) + (l & 15);
  const u32x2* aB0 = (const u32x2*)adjI + ((size_t)(bh * 64 + rg0) << 10);
  const u32x2* aB1 = aB0 + 1024;
  const ushort8* bB = (const ushort8*)supF + ((size_t)bh << 13);

  auto loadA = [&](int kt, u32x2* qa) {
    qa[0] = aB0[kt * 64 + lane20];
    qa[1] = aB0[kt * 64 + lane20 + 32];
    qa[2] = aB1[kt * 64 + lane20];
    qa[3] = aB1[kt * 64 + lane20 + 32];
  };
  auto loadAf32 = [&](int kt, ushort8* fa) {
#pragma unroll
    for (int gs = 0; gs < 4; ++gs) {
      const int g = gs >> 1, s2 = gs & 1;
      const float* src = adj + ((size_t)bh << 20) +
                         ((size_t)((rg0 + g) * 16 + (l & 15)) << 10) +
                         kt * 64 + s2 * 32 + ((l >> 4) << 3);
      f32x4 a = *(const f32x4*)(src);
      f32x4 b = *(const f32x4*)(src + 4);
      ushort8 u;
      u[0] = f2bf(a[0]); u[1] = f2bf(a[1]); u[2] = f2bf(a[2]); u[3] = f2bf(a[3]);
      u[4] = f2bf(b[0]); u[5] = f2bf(b[1]); u[6] = f2bf(b[2]); u[7] = f2bf(b[3]);
      fa[gs] = u;
    }
  };
  auto loadB = [&](int kt, ushort8* vb) {
#pragma unroll
    for (int c2 = 0; c2 < 8; ++c2) vb[c2] = bB[(size_t)kt * 512 + c2 * 64 + l];
  };

  f32x4 acc[2][4] = {};
  auto compute = [&](u32x2* qa, ushort8* fa, ushort8* vb) {
#pragma unroll
    for (int g = 0; g < 2; ++g)
#pragma unroll
      for (int s2 = 0; s2 < 2; ++s2) {
        bf16x8 a;
        if (PRE) {
          const unsigned v = qa[g * 2 + s2][hh];
          ushort8 ua;
#pragma unroll
          for (int e = 0; e < 8; ++e)
            ua[e] = (unsigned short)(__float_as_uint((float)((v >> (4 * e)) & 15u)) >> 16);
          a = asbf(ua);
        } else {
          a = asbf(fa[g * 2 + s2]);
        }
#pragma unroll
        for (int fj = 0; fj < 4; ++fj)
          acc[g][fj] = __builtin_amdgcn_mfma_f32_16x16x32_bf16(
              a, asbf(vb[s2 * 4 + fj]), acc[g][fj], 0, 0, 0);
      }
  };

  u32x2 qaE[4], qaO[4];
  ushort8 faE[4], faO[4], vbE[8], vbO[8];
  if (PRE) loadA(0, qaE); else loadAf32(0, faE);
  loadB(0, vbE);
  for (int kt = 0; kt < 16; kt += 2) {       // E/O static reg sets (rule #20)
    if (kt + 1 < 16) { if (PRE) loadA(kt + 1, qaO); else loadAf32(kt + 1, faO); loadB(kt + 1, vbO); }
    compute(qaE, faE, vbE);
    if (kt + 2 < 16) { if (PRE) loadA(kt + 2, qaE); else loadAf32(kt + 2, faE); loadB(kt + 2, vbE); }
    compute(qaO, faO, vbO);
  }

  const int el = l & 15, q4 = (l >> 4) * 4;
  const float qs = PRE ? (1.f / 15.f) : 1.f;
#pragma unroll
  for (int g = 0; g < 2; ++g) {
    const int rowb = (rg0 + g) * 16 + q4;
    float dgv[4];
#pragma unroll
    for (int reg = 0; reg < 4; ++reg)
      dgv[reg] = deg[(bh << 10) + rowb + reg] * qs;
#pragma unroll
    for (int fj = 0; fj < 4; ++fj) {
      const float bv = bias[fj * 16 + el];
#pragma unroll
      for (int reg = 0; reg < 4; ++reg) {
        const float val = acc[g][fj][reg] * dgv[reg] + bv;
        __builtin_nontemporal_store(
            val, out + ((size_t)bh << 16) + (size_t)(rowb + reg) * 64 + fj * 16 + el);
      }
    }
  }
}

extern "C" void kernel_launch(void* const* d_in, const int* in_sizes, int n_in,
                              void* d_out, int out_size, void* d_ws, size_t ws_size,
                              hipStream_t stream) {
  const float* X    = (const float*)d_in[0];  // [8,8,1024,64]
  const float* adj  = (const float*)d_in[1];  // [8,8,1024,1024]
  const float* W    = (const float*)d_in[2];  // [8,64,64]
  const float* bias = (const float*)d_in[3];  // [64]
  float* out = (float*)d_out;

  float* deg = (float*)d_ws;                                         // 256 KB
  unsigned short* supF = (unsigned short*)((char*)d_ws + 262144);    // 8 MB
  unsigned short* adjI = (unsigned short*)((char*)d_ws + 8650752);   // 32 MB (u4)
  const bool pre = ws_size >= 42205184ull;

  if (pre) {
    k_degsup<true><<<dim3(1024), dim3(256), 0, stream>>>(adj, X, W, adjI, deg, supF);
    k_gcn<true><<<dim3(512), dim3(256), 0, stream>>>(adj, adjI, supF, deg, bias, out);
  } else {
    k_degsup<false><<<dim3(1024), dim3(256), 0, stream>>>(adj, X, W, adjI, deg, supF);
    k_gcn<false><<<dim3(512), dim3(256), 0, stream>>>(adj, adjI, supF, deg, bias, out);
  }
}